// Round 6
// baseline (150.107 us; speedup 1.0000x reference)
//
#include <hip/hip_runtime.h>
#include <hip/hip_fp16.h>

#define B_     4096
#define INE_   4096
#define INBR_  8192
#define D_     2048
#define KE_    50
#define KPAD_  52
#define CAP_   512
#define NSL_   4      // BN-stat slices

// ---------- helpers ----------
__device__ __forceinline__ unsigned packh2(float a, float b) {
  __half2 h = __floats2half2_rn(a, b);
  return __builtin_bit_cast(unsigned, h);
}
__device__ __forceinline__ float2 unpackh2(unsigned u) {
  __half2 h = __builtin_bit_cast(__half2, u);
  return __half22float2(h);
}

// ---------- top-k body (proven R2-R5), now a device function ----------
__device__ void topk_body(const float* __restrict__ W, int row, int k, int kpad,
                          float hi, float t0, float vscale,
                          unsigned* __restrict__ out_off, float* __restrict__ out_val)
{
  const int t = threadIdx.x;
  const float* wr = W + (size_t)row * INE_;

  __shared__ float cval[CAP_];
  __shared__ int   ccol[CAP_];
  __shared__ int   scnt;
  __shared__ int   red[4];

  float thr = t0;
  int M = 0;
  for (int attempt = 0; attempt < 8; ++attempt) {
    int local = 0;
    #pragma unroll
    for (int j = 0; j < 4; ++j) {
      float4 w4 = *reinterpret_cast<const float4*>(wr + 4 * (t + 256 * j));
      local += (w4.x > thr) + (w4.y > thr) + (w4.z > thr) + (w4.w > thr);
    }
    #pragma unroll
    for (int off = 32; off > 0; off >>= 1) local += __shfl_down(local, off);
    if ((t & 63) == 0) red[t >> 6] = local;
    __syncthreads();
    M = red[0] + red[1] + red[2] + red[3];
    __syncthreads();
    if (M >= k && M <= CAP_) break;
    if (M < k) thr = hi - (hi - thr) * 4.0f;
    else       thr = hi - (hi - thr) * 0.5f;
  }

  if (t == 0) scnt = 0;
  __syncthreads();
  #pragma unroll
  for (int j = 0; j < 4; ++j) {
    int cbase = 4 * (t + 256 * j);
    float4 w4 = *reinterpret_cast<const float4*>(wr + cbase);
    float wv[4] = {w4.x, w4.y, w4.z, w4.w};
    #pragma unroll
    for (int q = 0; q < 4; ++q) {
      if (wv[q] > thr) {
        int pp = atomicAdd(&scnt, 1);
        if (pp < CAP_) { cval[pp] = wv[q]; ccol[pp] = cbase + q; }
      }
    }
  }
  __syncthreads();
  M = scnt < CAP_ ? scnt : CAP_;

  for (int i = t; i < M; i += 256) {
    float wi = cval[i]; int ci = ccol[i];
    int rank = 0;
    for (int m = 0; m < M; ++m) {
      float wm = cval[m]; int cm = ccol[m];
      rank += (wm > wi || (wm == wi && cm < ci)) ? 1 : 0;
    }
    if (rank < k) {
      unsigned c = (unsigned)ci;
      // pre-swizzled LDS byte offset: 8*s(c), s(c) = (c>>2) | ((c&3)<<10)
      unsigned off = ((c >> 2) << 3) | ((c & 3u) << 13);
      float    val = wi * vscale;
      if (kpad == 1) {
        out_off[row] = off;
        out_val[row] = val;
      } else {
        size_t idx = ((size_t)(rank >> 2) * D_ + row) * 4 + (rank & 3);
        out_off[idx] = off;
        out_val[idx] = val;
      }
    }
  }
  if (kpad > 1 && t < kpad - k) {
    int slot = k + t;
    size_t idx = ((size_t)(slot >> 2) * D_ + row) * 4 + (slot & 3);
    out_off[idx] = 0u;
    out_val[idx] = 0.0f;
  }
}

// ---------- K1: combined prep (topk exc, topk inh, diag extract) ----------
__global__ __launch_bounds__(256) void prep_kernel(
    const float* __restrict__ wexc, const float* __restrict__ winh,
    const float* __restrict__ wblk,
    unsigned* __restrict__ soT, float* __restrict__ veT,
    unsigned* __restrict__ so_inh, float* __restrict__ vi_inh,
    float* __restrict__ wdiag)
{
  const int bid = blockIdx.x;
  const float hi = 0.015625f;   // 1/sqrt(4096) fan-in bound
  if (bid < 2048) {
    topk_body(wexc, bid, KE_, KPAD_, hi, hi * (1.0f - 200.0f / 4096.0f), 1.0f,
              soT, veT);
  } else if (bid < 4096) {
    topk_body(winh, bid - 2048, 1, 1, hi, hi * (1.0f - 48.0f / 4096.0f), -50.0f,
              so_inh, vi_inh);
  } else {
    const int t = threadIdx.x;
    #pragma unroll
    for (int j = 0; j < 8; ++j) {
      int d = t + 256 * j;
      float4 w = *reinterpret_cast<const float4*>(wblk + (size_t)d * (INBR_ + 4));
      reinterpret_cast<float4*>(wdiag)[d] = w;
    }
  }
}

// ---------- K2: fused sparse-gather act computation (4 rows/block) ----------
// LDS: column c at words {2*s(c), 2*s(c)+1}; word 2*s(c)+p = half2(row 2p, 2p+1).
__device__ __forceinline__ void stage_rows4(const float* __restrict__ src,
                                            unsigned* xs, int b0, int p, int Q) {
  const float* r0p = src + (size_t)(b0 + 2 * p)     * INE_;
  const float* r1p = src + (size_t)(b0 + 2 * p + 1) * INE_;
  #pragma unroll
  for (int m = 0; m < 4; ++m) {
    int c0 = 4 * Q + 1024 * m;
    float4 fa = *reinterpret_cast<const float4*>(r0p + c0);
    float4 fb = *reinterpret_cast<const float4*>(r1p + c0);
    int wb = 2 * (Q + 256 * m) + p;
    xs[wb]        = packh2(fa.x, fb.x);
    xs[wb + 2048] = packh2(fa.y, fb.y);
    xs[wb + 4096] = packh2(fa.z, fb.z);
    xs[wb + 6144] = packh2(fa.w, fb.w);
  }
}

__device__ __forceinline__ uint2 ldg2(const char* ldsb, unsigned off) {
  return *reinterpret_cast<const uint2*>(ldsb + off);
}

#define FMA4(R, G, WV) do {                                                \
    float2 f0 = unpackh2((G).x), f1 = unpackh2((G).y);                     \
    acc[R][0] = fmaf(f0.x, (WV), acc[R][0]);                               \
    acc[R][1] = fmaf(f0.y, (WV), acc[R][1]);                               \
    acc[R][2] = fmaf(f1.x, (WV), acc[R][2]);                               \
    acc[R][3] = fmaf(f1.y, (WV), acc[R][3]);                               \
  } while (0)

// one excitation gather iteration (ii may be runtime; acc indices compile-time)
#define GATHER_ITER(II) do {                                               \
    uint4 o_[4]; float4 v_[4];                                             \
    _Pragma("unroll")                                                      \
    for (int r = 0; r < 4; ++r) {                                          \
      o_[r] = soT4[(II) * D_ + t + 512 * r];                               \
      v_[r] = veT4[(II) * D_ + t + 512 * r];                               \
    }                                                                      \
    uint2 gq_[4][4];                                                       \
    _Pragma("unroll")                                                      \
    for (int r = 0; r < 4; ++r) {                                          \
      gq_[r][0] = ldg2(ldsb, o_[r].x);                                     \
      gq_[r][1] = ldg2(ldsb, o_[r].y);                                     \
      gq_[r][2] = ldg2(ldsb, o_[r].z);                                     \
      gq_[r][3] = ldg2(ldsb, o_[r].w);                                     \
    }                                                                      \
    _Pragma("unroll")                                                      \
    for (int r = 0; r < 4; ++r) {                                          \
      FMA4(r, gq_[r][0], v_[r].x);                                         \
      FMA4(r, gq_[r][1], v_[r].y);                                         \
      FMA4(r, gq_[r][2], v_[r].z);                                         \
      FMA4(r, gq_[r][3], v_[r].w);                                         \
    }                                                                      \
  } while (0)

// block-diagonal chunk for compile-time R_ (streams xbr inside the E phase)
#define BR_CHUNK(R_) do {                                                  \
    const int d_ = t + 512 * (R_);                                         \
    float4 wb4 = reinterpret_cast<const float4*>(wdiag)[d_];               \
    _Pragma("unroll")                                                      \
    for (int b = 0; b < 4; ++b) {                                          \
      float4 xb4 = *reinterpret_cast<const float4*>(                       \
          xbr + (size_t)(b0 + b) * INBR_ + 4 * d_);                        \
      acc[R_][b] += xb4.x * wb4.x + xb4.y * wb4.y +                        \
                    xb4.z * wb4.z + xb4.w * wb4.w;                         \
    }                                                                      \
  } while (0)

__global__ __launch_bounds__(512, 4) void fused_main(
    const float* __restrict__ xe, const float* __restrict__ xi,
    const float* __restrict__ xbr, const float* __restrict__ wdiag,
    const unsigned* __restrict__ soT, const float* __restrict__ veT,
    const unsigned* __restrict__ so_inh, const float* __restrict__ vi_inh,
    float* __restrict__ act, float* __restrict__ sums_p,
    float* __restrict__ sumsq_p)
{
  __shared__ unsigned xs[8192];           // 32 KiB
  const int t  = threadIdx.x;
  const int b0 = blockIdx.x * 4;
  const int p  = t & 1;
  const int Q  = t >> 1;

  float acc[4][4];
  #pragma unroll
  for (int r = 0; r < 4; ++r)
    #pragma unroll
    for (int b = 0; b < 4; ++b) acc[r][b] = 0.0f;

  const char* ldsb = reinterpret_cast<const char*>(xs);
  const uint4*  soT4 = reinterpret_cast<const uint4*>(soT);
  const float4* veT4 = reinterpret_cast<const float4*>(veT);

  // ---- stage xe into LDS ----
  stage_rows4(xe, xs, b0, p, Q);
  __syncthreads();

  // ---- prefetch xi rows into registers (T14: hides xi HBM under E loop) ----
  float4 xia[4], xib[4];
  {
    const float* xr0 = xi + (size_t)(b0 + 2 * p)     * INE_;
    const float* xr1 = xi + (size_t)(b0 + 2 * p + 1) * INE_;
    #pragma unroll
    for (int m = 0; m < 4; ++m) {
      xia[m] = *reinterpret_cast<const float4*>(xr0 + 4 * Q + 1024 * m);
      xib[m] = *reinterpret_cast<const float4*>(xr1 + 4 * Q + 1024 * m);
    }
  }
  // prefetch inhibition metadata (tiny)
  unsigned oi[4]; float viv[4];
  #pragma unroll
  for (int r = 0; r < 4; ++r) {
    oi[r]  = so_inh[t + 512 * r];
    viv[r] = vi_inh[t + 512 * r];
  }

  // ---- phase E: 13 gather iterations, xbr streaming interleaved ----
  #pragma unroll
  for (int g = 0; g < 4; ++g) {
    for (int jj = 0; jj < 3; ++jj) {    // rolled; ii runtime is fine
      int ii = 3 * g + jj;
      GATHER_ITER(ii);
    }
    BR_CHUNK(g);                        // compile-time r = g
  }
  GATHER_ITER(12);
  __syncthreads();                      // all xe reads done

  // ---- write xi from registers, then inhibition gather ----
  #pragma unroll
  for (int m = 0; m < 4; ++m) {
    int wb = 2 * (Q + 256 * m) + p;
    xs[wb]        = packh2(xia[m].x, xib[m].x);
    xs[wb + 2048] = packh2(xia[m].y, xib[m].y);
    xs[wb + 4096] = packh2(xia[m].z, xib[m].z);
    xs[wb + 6144] = packh2(xia[m].w, xib[m].w);
  }
  __syncthreads();
  {
    uint2 gi[4];
    #pragma unroll
    for (int r = 0; r < 4; ++r) gi[r] = ldg2(ldsb, oi[r]);
    #pragma unroll
    for (int r = 0; r < 4; ++r) FMA4(r, gi[r], viv[r]);
  }

  // ---- write act + sliced BN partials ----
  const int slice = blockIdx.x >> 8;    // 0..3
  #pragma unroll
  for (int r = 0; r < 4; ++r) {
    const int d = t + 512 * r;
    float s = 0.0f, s2 = 0.0f;
    #pragma unroll
    for (int b = 0; b < 4; ++b) {
      float a = acc[r][b];
      act[(size_t)(b0 + b) * D_ + d] = a;
      s += a;
      s2 = fmaf(a, a, s2);
    }
    atomicAdd(&sums_p[slice * D_ + d], s);     // 256 adds/address total
    atomicAdd(&sumsq_p[slice * D_ + d], s2);
  }
}

// ---------- K3: fused stats-finalize + normalize + sigmoid (in place) ----------
__global__ __launch_bounds__(256) void tail_kernel(
    float* __restrict__ act, const float* __restrict__ sums_p,
    const float* __restrict__ sumsq_p, const float* __restrict__ gamma,
    const float* __restrict__ beta)
{
  __shared__ float scsh[2 * D_];        // 16 KiB
  const int tid = threadIdx.x;
  #pragma unroll
  for (int j = 0; j < 8; ++j) {
    int d = tid + 256 * j;
    float s = 0.0f, s2 = 0.0f;
    #pragma unroll
    for (int sl = 0; sl < NSL_; ++sl) {
      s  += sums_p[sl * D_ + d];
      s2 += sumsq_p[sl * D_ + d];
    }
    float mean = s  * (1.0f / B_);
    float var  = s2 * (1.0f / B_) - mean * mean;
    float rstd = rsqrtf(var + 1e-5f);
    float sc   = gamma[d] * rstd;
    scsh[2 * d]     = sc;
    scsh[2 * d + 1] = fmaf(-mean, sc, beta[d]);
  }
  __syncthreads();

  const int r0 = blockIdx.x * 8;        // 512 blocks x 8 rows
  for (int rr = 0; rr < 8; ++rr) {
    float4* rowp = reinterpret_cast<float4*>(act + (size_t)(r0 + rr) * D_);
    #pragma unroll
    for (int i2 = 0; i2 < 2; ++i2) {
      int i = tid + 256 * i2;
      float4 a = rowp[i];
      const float4* sp = reinterpret_cast<const float4*>(scsh + 8 * i);
      float4 s0 = sp[0];   // (sc0, sh0, sc1, sh1)
      float4 s1 = sp[1];   // (sc2, sh2, sc3, sh3)
      float z0 = fmaf(a.x, s0.x, s0.y);
      float z1 = fmaf(a.y, s0.z, s0.w);
      float z2 = fmaf(a.z, s1.x, s1.y);
      float z3 = fmaf(a.w, s1.z, s1.w);
      a.x = 1.0f / (1.0f + __expf(-z0));
      a.y = 1.0f / (1.0f + __expf(-z1));
      a.z = 1.0f / (1.0f + __expf(-z2));
      a.w = 1.0f / (1.0f + __expf(-z3));
      rowp[i] = a;
    }
  }
}

extern "C" void kernel_launch(void* const* d_in, const int* in_sizes, int n_in,
                              void* d_out, int out_size, void* d_ws, size_t ws_size,
                              hipStream_t stream) {
  const float* xe    = (const float*)d_in[0];
  const float* xi    = (const float*)d_in[1];
  const float* xbr   = (const float*)d_in[2];
  const float* wexc  = (const float*)d_in[3];
  const float* winh  = (const float*)d_in[4];
  const float* wblk  = (const float*)d_in[5];
  const float* gamma = (const float*)d_in[6];
  const float* beta  = (const float*)d_in[7];
  float* act = (float*)d_out;

  char* ws = (char*)d_ws;
  unsigned* soT     = (unsigned*)(ws + 0);        // [13][2048][4] u32
  float*    veT     = (float*)   (ws + 425984);   // [13][2048][4] f32
  unsigned* so_inh  = (unsigned*)(ws + 851968);   // [2048] u32
  float*    vi_inh  = (float*)   (ws + 860160);   // [2048] f32
  float*    wdiag   = (float*)   (ws + 868352);   // [2048][4] f32
  float*    sums_p  = (float*)   (ws + 901120);   // [4][2048] f32
  float*    sumsq_p = (float*)   (ws + 933888);   // [4][2048] f32 (end 966656)

  hipMemsetAsync(sums_p, 0, 2 * NSL_ * D_ * sizeof(float), stream);

  prep_kernel<<<dim3(4097), dim3(256), 0, stream>>>(
      wexc, winh, wblk, soT, veT, so_inh, vi_inh, wdiag);
  fused_main<<<dim3(B_ / 4), dim3(512), 0, stream>>>(
      xe, xi, xbr, wdiag, soT, veT, so_inh, vi_inh, act, sums_p, sumsq_p);
  tail_kernel<<<dim3(512), dim3(256), 0, stream>>>(
      act, sums_p, sumsq_p, gamma, beta);
}

// Round 7
// 135.650 us; speedup vs baseline: 1.1066x; 1.1066x over previous
//
#include <hip/hip_runtime.h>
#include <hip/hip_fp16.h>

#define B_     4096
#define INE_   4096
#define INBR_  8192
#define D_     2048
#define KE_    50
#define KPAD_  52
#define CAP_   512

// ---------- helpers ----------
__device__ __forceinline__ unsigned packh2(float a, float b) {
  __half2 h = __floats2half2_rn(a, b);
  return __builtin_bit_cast(unsigned, h);
}
__device__ __forceinline__ float2 unpackh2(unsigned u) {
  __half2 h = __builtin_bit_cast(__half2, u);
  return __half22float2(h);
}

// ---------- top-k body (proven R2-R6) ----------
// Emits pre-swizzled LDS byte offsets for the 8-row uint4 layout:
//   s(c) = (c>>2) | ((c&3)<<10),  byte = 16*s(c) = ((c>>2)<<4) | ((c&3)<<14)
__device__ void topk_body(const float* __restrict__ W, int row, int k, int kpad,
                          float hi, float t0, float vscale,
                          unsigned* __restrict__ out_off, float* __restrict__ out_val)
{
  const int t = threadIdx.x;
  const float* wr = W + (size_t)row * INE_;

  __shared__ float cval[CAP_];
  __shared__ int   ccol[CAP_];
  __shared__ int   scnt;
  __shared__ int   red[4];

  float thr = t0;
  int M = 0;
  for (int attempt = 0; attempt < 8; ++attempt) {
    int local = 0;
    #pragma unroll
    for (int j = 0; j < 4; ++j) {
      float4 w4 = *reinterpret_cast<const float4*>(wr + 4 * (t + 256 * j));
      local += (w4.x > thr) + (w4.y > thr) + (w4.z > thr) + (w4.w > thr);
    }
    #pragma unroll
    for (int off = 32; off > 0; off >>= 1) local += __shfl_down(local, off);
    if ((t & 63) == 0) red[t >> 6] = local;
    __syncthreads();
    M = red[0] + red[1] + red[2] + red[3];
    __syncthreads();
    if (M >= k && M <= CAP_) break;
    if (M < k) thr = hi - (hi - thr) * 4.0f;
    else       thr = hi - (hi - thr) * 0.5f;
  }

  if (t == 0) scnt = 0;
  __syncthreads();
  #pragma unroll
  for (int j = 0; j < 4; ++j) {
    int cbase = 4 * (t + 256 * j);
    float4 w4 = *reinterpret_cast<const float4*>(wr + cbase);
    float wv[4] = {w4.x, w4.y, w4.z, w4.w};
    #pragma unroll
    for (int q = 0; q < 4; ++q) {
      if (wv[q] > thr) {
        int pp = atomicAdd(&scnt, 1);
        if (pp < CAP_) { cval[pp] = wv[q]; ccol[pp] = cbase + q; }
      }
    }
  }
  __syncthreads();
  M = scnt < CAP_ ? scnt : CAP_;

  for (int i = t; i < M; i += 256) {
    float wi = cval[i]; int ci = ccol[i];
    int rank = 0;
    for (int m = 0; m < M; ++m) {
      float wm = cval[m]; int cm = ccol[m];
      rank += (wm > wi || (wm == wi && cm < ci)) ? 1 : 0;
    }
    if (rank < k) {
      unsigned c = (unsigned)ci;
      unsigned off = ((c >> 2) << 4) | ((c & 3u) << 14);
      float    val = wi * vscale;
      if (kpad == 1) {
        out_off[row] = off;
        out_val[row] = val;
      } else {
        size_t idx = ((size_t)(rank >> 2) * D_ + row) * 4 + (rank & 3);
        out_off[idx] = off;
        out_val[idx] = val;
      }
    }
  }
  if (kpad > 1 && t < kpad - k) {
    int slot = k + t;
    size_t idx = ((size_t)(slot >> 2) * D_ + row) * 4 + (slot & 3);
    out_off[idx] = 0u;
    out_val[idx] = 0.0f;
  }
}

// ---------- K1: combined prep (topk exc, topk inh, diag extract) ----------
__global__ __launch_bounds__(256) void prep_kernel(
    const float* __restrict__ wexc, const float* __restrict__ winh,
    const float* __restrict__ wblk,
    unsigned* __restrict__ soT, float* __restrict__ veT,
    unsigned* __restrict__ so_inh, float* __restrict__ vi_inh,
    float* __restrict__ wdiag)
{
  const int bid = blockIdx.x;
  const float hi = 0.015625f;   // 1/sqrt(4096) fan-in bound
  if (bid < 2048) {
    topk_body(wexc, bid, KE_, KPAD_, hi, hi * (1.0f - 200.0f / 4096.0f), 1.0f,
              soT, veT);
  } else if (bid < 4096) {
    topk_body(winh, bid - 2048, 1, 1, hi, hi * (1.0f - 48.0f / 4096.0f), -50.0f,
              so_inh, vi_inh);
  } else {
    const int t = threadIdx.x;
    #pragma unroll
    for (int j = 0; j < 8; ++j) {
      int d = t + 256 * j;
      float4 w = *reinterpret_cast<const float4*>(wblk + (size_t)d * (INBR_ + 4));
      reinterpret_cast<float4*>(wdiag)[d] = w;
    }
  }
}

// ---------- K2a: E+I sparse gather (8 rows/block, 64 KiB LDS) ----------
// LDS: column c at bytes [16*s(c) .. 16*s(c)+15]; word 4*s(c)+p = half2(row 2p, 2p+1).
__device__ __forceinline__ void stage_rows8(const float* __restrict__ src,
                                            unsigned* xs, int b0, int p, int Q) {
  const float* r0p = src + (size_t)(b0 + 2 * p)     * INE_;
  const float* r1p = src + (size_t)(b0 + 2 * p + 1) * INE_;
  #pragma unroll
  for (int m = 0; m < 8; ++m) {
    int c0 = 4 * Q + 512 * m;
    float4 fa = *reinterpret_cast<const float4*>(r0p + c0);
    float4 fb = *reinterpret_cast<const float4*>(r1p + c0);
    int wb = 4 * (Q + 128 * m) + p;
    xs[wb]          = packh2(fa.x, fb.x);
    xs[wb + 4096]   = packh2(fa.y, fb.y);
    xs[wb + 8192]   = packh2(fa.z, fb.z);
    xs[wb + 12288]  = packh2(fa.w, fb.w);
  }
}

__device__ __forceinline__ uint4 ld16(const char* ldsb, unsigned off) {
  return *reinterpret_cast<const uint4*>(ldsb + off);
}

#define FMA8(R, G, WV) do {                                                \
    float2 f0 = unpackh2((G).x), f1 = unpackh2((G).y);                     \
    float2 f2 = unpackh2((G).z), f3 = unpackh2((G).w);                     \
    acc[R][0] = fmaf(f0.x, (WV), acc[R][0]);                               \
    acc[R][1] = fmaf(f0.y, (WV), acc[R][1]);                               \
    acc[R][2] = fmaf(f1.x, (WV), acc[R][2]);                               \
    acc[R][3] = fmaf(f1.y, (WV), acc[R][3]);                               \
    acc[R][4] = fmaf(f2.x, (WV), acc[R][4]);                               \
    acc[R][5] = fmaf(f2.y, (WV), acc[R][5]);                               \
    acc[R][6] = fmaf(f3.x, (WV), acc[R][6]);                               \
    acc[R][7] = fmaf(f3.y, (WV), acc[R][7]);                               \
  } while (0)

__global__ __launch_bounds__(512, 4) void ei_kernel(
    const float* __restrict__ xe, const float* __restrict__ xi,
    const unsigned* __restrict__ soT, const float* __restrict__ veT,
    const unsigned* __restrict__ so_inh, const float* __restrict__ vi_inh,
    float* __restrict__ act)
{
  __shared__ unsigned xs[16384];          // 64 KiB -> 2 blocks/CU
  const int t  = threadIdx.x;
  const int b0 = blockIdx.x * 8;
  const int p  = t & 3;
  const int Q  = t >> 2;

  float acc[4][8];
  #pragma unroll
  for (int r = 0; r < 4; ++r)
    #pragma unroll
    for (int b = 0; b < 8; ++b) acc[r][b] = 0.0f;

  const char* ldsb = reinterpret_cast<const char*>(xs);
  const uint4*  soT4 = reinterpret_cast<const uint4*>(soT);
  const float4* veT4 = reinterpret_cast<const float4*>(veT);

  // ---- phase E ----
  stage_rows8(xe, xs, b0, p, Q);
  __syncthreads();
  for (int ii = 0; ii < KPAD_ / 4; ++ii) {
    uint4 o[4]; float4 v[4];
    #pragma unroll
    for (int r = 0; r < 4; ++r) {
      o[r] = soT4[ii * D_ + t + 512 * r];
      v[r] = veT4[ii * D_ + t + 512 * r];
    }
    // r-pair 0,1: 8 ds_read_b128 in flight, then consume
    {
      uint4 g[2][4];
      #pragma unroll
      for (int rr = 0; rr < 2; ++rr) {
        g[rr][0] = ld16(ldsb, o[rr].x);
        g[rr][1] = ld16(ldsb, o[rr].y);
        g[rr][2] = ld16(ldsb, o[rr].z);
        g[rr][3] = ld16(ldsb, o[rr].w);
      }
      #pragma unroll
      for (int rr = 0; rr < 2; ++rr) {
        FMA8(rr, g[rr][0], v[rr].x);
        FMA8(rr, g[rr][1], v[rr].y);
        FMA8(rr, g[rr][2], v[rr].z);
        FMA8(rr, g[rr][3], v[rr].w);
      }
    }
    // r-pair 2,3
    {
      uint4 g[2][4];
      #pragma unroll
      for (int rr = 0; rr < 2; ++rr) {
        g[rr][0] = ld16(ldsb, o[2 + rr].x);
        g[rr][1] = ld16(ldsb, o[2 + rr].y);
        g[rr][2] = ld16(ldsb, o[2 + rr].z);
        g[rr][3] = ld16(ldsb, o[2 + rr].w);
      }
      #pragma unroll
      for (int rr = 0; rr < 2; ++rr) {
        FMA8(2 + rr, g[rr][0], v[2 + rr].x);
        FMA8(2 + rr, g[rr][1], v[2 + rr].y);
        FMA8(2 + rr, g[rr][2], v[2 + rr].z);
        FMA8(2 + rr, g[rr][3], v[2 + rr].w);
      }
    }
  }
  __syncthreads();

  // ---- phase I ----
  stage_rows8(xi, xs, b0, p, Q);
  unsigned oi[4]; float viv[4];
  #pragma unroll
  for (int r = 0; r < 4; ++r) {
    oi[r]  = so_inh[t + 512 * r];
    viv[r] = vi_inh[t + 512 * r];
  }
  __syncthreads();
  {
    uint4 gi[4];
    #pragma unroll
    for (int r = 0; r < 4; ++r) gi[r] = ld16(ldsb, oi[r]);
    #pragma unroll
    for (int r = 0; r < 4; ++r) FMA8(r, gi[r], viv[r]);
  }

  // ---- write act ----
  #pragma unroll
  for (int r = 0; r < 4; ++r) {
    const int d = t + 512 * r;
    #pragma unroll
    for (int b = 0; b < 8; ++b)
      act[(size_t)(b0 + b) * D_ + d] = acc[r][b];
  }
}

// ---------- K2b: block-diagonal depolarization, pure stream ----------
__global__ __launch_bounds__(256) void br_kernel(
    const float* __restrict__ xbr, const float* __restrict__ wdiag,
    float* __restrict__ act)
{
  const float4* xbr4 = reinterpret_cast<const float4*>(xbr);
  const float4* wd4  = reinterpret_cast<const float4*>(wdiag);
  float4*       act4 = reinterpret_cast<float4*>(act);
  const int total = B_ * D_ / 4;          // 2M float4 elements of act
  for (int i = blockIdx.x * 256 + threadIdx.x; i < total;
       i += gridDim.x * 256) {
    int b  = i >> 9;                      // row (D_/4 = 512)
    int dq = i & 511;                     // float4-index within row
    float4 a = act4[i];
    const float4* xp = xbr4 + (size_t)b * (INBR_ / 4) + 4 * dq;
    float4 x0 = xp[0], x1 = xp[1], x2 = xp[2], x3 = xp[3];
    float4 w0 = wd4[4 * dq], w1 = wd4[4 * dq + 1],
           w2 = wd4[4 * dq + 2], w3 = wd4[4 * dq + 3];
    a.x += x0.x * w0.x + x0.y * w0.y + x0.z * w0.z + x0.w * w0.w;
    a.y += x1.x * w1.x + x1.y * w1.y + x1.z * w1.z + x1.w * w1.w;
    a.z += x2.x * w2.x + x2.y * w2.y + x2.z * w2.z + x2.w * w2.w;
    a.w += x3.x * w3.x + x3.y * w3.y + x3.z * w3.z + x3.w * w3.w;
    act4[i] = a;
  }
}

// ---------- K3a: column sums/sumsq over act (proven R2) ----------
__global__ __launch_bounds__(256) void reduce_stats(
    const float* __restrict__ act, float* __restrict__ sums,
    float* __restrict__ sumsq)
{
  const int dg = blockIdx.x & 63;
  const int rg = blockIdx.x >> 6;
  const int tx = threadIdx.x & 31;
  const int ty = threadIdx.x >> 5;
  const int d  = dg * 32 + tx;

  float s = 0.0f, s2 = 0.0f;
  #pragma unroll 4
  for (int i = 0; i < 64; ++i) {
    int row = rg * 512 + ty + 8 * i;
    float a = act[(size_t)row * D_ + d];
    s += a;
    s2 = fmaf(a, a, s2);
  }
  __shared__ float ls[2][8][32];
  ls[0][ty][tx] = s;
  ls[1][ty][tx] = s2;
  __syncthreads();
  if (ty == 0) {
    #pragma unroll
    for (int j = 1; j < 8; ++j) { s += ls[0][j][tx]; s2 += ls[1][j][tx]; }
    atomicAdd(&sums[d], s);
    atomicAdd(&sumsq[d], s2);
  }
}

// ---------- K3b: fused finalize + normalize + sigmoid (in place) ----------
__global__ __launch_bounds__(256) void tail_kernel(
    float* __restrict__ act, const float* __restrict__ sums,
    const float* __restrict__ sumsq, const float* __restrict__ gamma,
    const float* __restrict__ beta)
{
  __shared__ float scsh[2 * D_];        // 16 KiB
  const int tid = threadIdx.x;
  #pragma unroll
  for (int j = 0; j < 8; ++j) {
    int d = tid + 256 * j;
    float mean = sums[d]  * (1.0f / B_);
    float var  = sumsq[d] * (1.0f / B_) - mean * mean;
    float rstd = rsqrtf(var + 1e-5f);
    float sc   = gamma[d] * rstd;
    scsh[2 * d]     = sc;
    scsh[2 * d + 1] = fmaf(-mean, sc, beta[d]);
  }
  __syncthreads();

  const int r0 = blockIdx.x * 8;
  for (int rr = 0; rr < 8; ++rr) {
    float4* rowp = reinterpret_cast<float4*>(act + (size_t)(r0 + rr) * D_);
    #pragma unroll
    for (int i2 = 0; i2 < 2; ++i2) {
      int i = tid + 256 * i2;
      float4 a = rowp[i];
      const float4* sp = reinterpret_cast<const float4*>(scsh + 8 * i);
      float4 s0 = sp[0];
      float4 s1 = sp[1];
      float z0 = fmaf(a.x, s0.x, s0.y);
      float z1 = fmaf(a.y, s0.z, s0.w);
      float z2 = fmaf(a.z, s1.x, s1.y);
      float z3 = fmaf(a.w, s1.z, s1.w);
      a.x = 1.0f / (1.0f + __expf(-z0));
      a.y = 1.0f / (1.0f + __expf(-z1));
      a.z = 1.0f / (1.0f + __expf(-z2));
      a.w = 1.0f / (1.0f + __expf(-z3));
      rowp[i] = a;
    }
  }
}

extern "C" void kernel_launch(void* const* d_in, const int* in_sizes, int n_in,
                              void* d_out, int out_size, void* d_ws, size_t ws_size,
                              hipStream_t stream) {
  const float* xe    = (const float*)d_in[0];
  const float* xi    = (const float*)d_in[1];
  const float* xbr   = (const float*)d_in[2];
  const float* wexc  = (const float*)d_in[3];
  const float* winh  = (const float*)d_in[4];
  const float* wblk  = (const float*)d_in[5];
  const float* gamma = (const float*)d_in[6];
  const float* beta  = (const float*)d_in[7];
  float* act = (float*)d_out;

  char* ws = (char*)d_ws;
  unsigned* soT    = (unsigned*)(ws + 0);        // [13][2048][4] u32
  float*    veT    = (float*)   (ws + 425984);   // [13][2048][4] f32
  unsigned* so_inh = (unsigned*)(ws + 851968);   // [2048] u32
  float*    vi_inh = (float*)   (ws + 860160);   // [2048] f32
  float*    wdiag  = (float*)   (ws + 868352);   // [2048][4] f32
  float*    sums   = (float*)   (ws + 901120);   // [2048] f32
  float*    sumsq  = (float*)   (ws + 909312);   // [2048] f32

  hipMemsetAsync(sums, 0, 2 * D_ * sizeof(float), stream);

  prep_kernel<<<dim3(4097), dim3(256), 0, stream>>>(
      wexc, winh, wblk, soT, veT, so_inh, vi_inh, wdiag);
  ei_kernel<<<dim3(B_ / 8), dim3(512), 0, stream>>>(
      xe, xi, soT, veT, so_inh, vi_inh, act);
  br_kernel<<<dim3(2048), dim3(256), 0, stream>>>(xbr, wdiag, act);
  reduce_stats<<<dim3(512), dim3(256), 0, stream>>>(act, sums, sumsq);
  tail_kernel<<<dim3(512), dim3(256), 0, stream>>>(
      act, sums, sumsq, gamma, beta);
}